// Round 1
// baseline (202.898 us; speedup 1.0000x reference)
//
#include <hip/hip_runtime.h>
#include <hip/hip_bf16.h>
#include <math.h>

typedef __bf16 bf16x8 __attribute__((ext_vector_type(8)));
typedef __bf16 bf16x2 __attribute__((ext_vector_type(2)));
typedef float  f32x4  __attribute__((ext_vector_type(4)));

constexpr int EMBED = 1024;
constexpr int NH    = 16;
constexpr int HD    = 64;
constexpr int LL    = 2048;
constexpr int BB    = 2;
constexpr int SSEQ  = 2048;

constexpr int BQ = 64;          // q rows per block (4 waves x 16)
constexpr int BK = 64;          // kv rows per tile
constexpr int NT = SSEQ / BK;   // 32 tiles

// LDS byte-swizzle: row-major [rows][128B] tiles, XOR bits 4-6 with row&7.
// Keeps 16B-aligned chunks intact; makes stride-128B column reads conflict-free.

__global__ __launch_bounds__(256) void sdpa_fwd(const float* __restrict__ Qg,
                                                const float* __restrict__ Kg,
                                                const float* __restrict__ Vg,
                                                float* __restrict__ Og) {
  __shared__ char ksh[BK * 128];        // K tile, bf16 [64 s][64 d], swizzled
  __shared__ char vtsh[HD * 128];       // V^T tile, bf16 [64 d][64 s], swizzled
  __shared__ char psh[4 * 16 * 128];    // per-wave P tile, bf16 [16 q][64 s], swizzled

  const int tid  = threadIdx.x;
  const int wv   = tid >> 6;
  const int lane = tid & 63;
  const int g    = lane >> 4;   // lane group 0..3
  const int qc   = lane & 15;   // "column" lane id

  const int bh = blockIdx.y;    // b*16 + h
  const int bb = bh >> 4;
  const int hh = bh & 15;

  const size_t rstride = (size_t)BB * EMBED;     // elements per sequence row
  const float* qb = Qg + (size_t)bb * EMBED + hh * HD;
  const float* kb = Kg + (size_t)bb * EMBED + hh * HD;
  const float* vb = Vg + (size_t)bb * EMBED + hh * HD;
  float*       ob = Og + (size_t)bb * EMBED + hh * HD;

  const int qrow0 = blockIdx.x * BQ + wv * 16;

  // ---- Q fragments in B-operand layout: lane holds Q[q=qc][d = f*32 + g*8 + j]
  bf16x8 qf[2];
  {
    const float* qr = qb + (size_t)(qrow0 + qc) * rstride;
#pragma unroll
    for (int f = 0; f < 2; ++f) {
      const float* p = qr + f * 32 + g * 8;
      float4 a = *(const float4*)p;
      float4 c = *(const float4*)(p + 4);
      qf[f][0] = (__bf16)(a.x * 0.125f);
      qf[f][1] = (__bf16)(a.y * 0.125f);
      qf[f][2] = (__bf16)(a.z * 0.125f);
      qf[f][3] = (__bf16)(a.w * 0.125f);
      qf[f][4] = (__bf16)(c.x * 0.125f);
      qf[f][5] = (__bf16)(c.y * 0.125f);
      qf[f][6] = (__bf16)(c.z * 0.125f);
      qf[f][7] = (__bf16)(c.w * 0.125f);
    }
  }

  f32x4 acc[4];
#pragma unroll
  for (int nb = 0; nb < 4; ++nb) { acc[nb][0] = 0.f; acc[nb][1] = 0.f; acc[nb][2] = 0.f; acc[nb][3] = 0.f; }
  float m = -INFINITY;
  float l = 0.f;

  for (int t = 0; t < NT; ++t) {
    // ---------------- stage K tile: bf16 [s][d], swizzled ----------------
    {
      const int r  = tid >> 2;            // 0..63 (kv row)
      const int c0 = (tid & 3) * 16;      // starting float col
      const float* kr = kb + (size_t)(t * BK + r) * rstride + c0;
      float4 x0 = *(const float4*)(kr);
      float4 x1 = *(const float4*)(kr + 4);
      float4 x2 = *(const float4*)(kr + 8);
      float4 x3 = *(const float4*)(kr + 12);
      bf16x8 w0, w1;
      w0[0] = (__bf16)x0.x; w0[1] = (__bf16)x0.y; w0[2] = (__bf16)x0.z; w0[3] = (__bf16)x0.w;
      w0[4] = (__bf16)x1.x; w0[5] = (__bf16)x1.y; w0[6] = (__bf16)x1.z; w0[7] = (__bf16)x1.w;
      w1[0] = (__bf16)x2.x; w1[1] = (__bf16)x2.y; w1[2] = (__bf16)x2.z; w1[3] = (__bf16)x2.w;
      w1[4] = (__bf16)x3.x; w1[5] = (__bf16)x3.y; w1[6] = (__bf16)x3.z; w1[7] = (__bf16)x3.w;
      const int base = r * 128;
      const int sw   = (r & 7) << 4;
      *(bf16x8*)(ksh + base + ((c0 * 2)      ^ sw)) = w0;
      *(bf16x8*)(ksh + base + ((c0 * 2 + 16) ^ sw)) = w1;
    }
    // ---------------- stage V^T tile: bf16 [d][s], swizzled ----------------
    {
      const int s2 = tid & 31;            // pair of kv rows 2*s2, 2*s2+1
      const int db = (tid >> 5) * 8;      // 8 head-dims per thread
      const float* v0 = vb + (size_t)(t * BK + 2 * s2) * rstride + db;
      const float* v1 = v0 + rstride;
      float4 a0 = *(const float4*)v0;
      float4 a1 = *(const float4*)(v0 + 4);
      float4 c0 = *(const float4*)v1;
      float4 c1 = *(const float4*)(v1 + 4);
      float av[8] = {a0.x, a0.y, a0.z, a0.w, a1.x, a1.y, a1.z, a1.w};
      float cv[8] = {c0.x, c0.y, c0.z, c0.w, c1.x, c1.y, c1.z, c1.w};
#pragma unroll
      for (int i = 0; i < 8; ++i) {
        const int d = db + i;
        bf16x2 pr;
        pr[0] = (__bf16)av[i];
        pr[1] = (__bf16)cv[i];
        *(bf16x2*)(vtsh + d * 128 + ((4 * s2) ^ ((d & 7) << 4))) = pr;
      }
    }
    __syncthreads();

    // ---------------- QK^T (swapped): S^T[s, q] = K · Q ----------------
    f32x4 st[4];
    {
      const int sw = (qc & 7) << 4;
#pragma unroll
      for (int sb = 0; sb < 4; ++sb) {
        const int base = (sb * 16 + qc) * 128;   // row = kv index; (row&7)==(qc&7)
        bf16x8 k0 = *(const bf16x8*)(ksh + base + ((g * 16)      ^ sw));
        bf16x8 k1 = *(const bf16x8*)(ksh + base + ((64 + g * 16) ^ sw));
        f32x4 a; a[0] = 0.f; a[1] = 0.f; a[2] = 0.f; a[3] = 0.f;
        a = __builtin_amdgcn_mfma_f32_16x16x32_bf16(k0, qf[0], a, 0, 0, 0);
        a = __builtin_amdgcn_mfma_f32_16x16x32_bf16(k1, qf[1], a, 0, 0, 0);
        st[sb] = a;
      }
    }

    // ---------------- online softmax (state per lane, q = qc) ----------------
    float mx = st[0][0];
#pragma unroll
    for (int sb = 0; sb < 4; ++sb)
#pragma unroll
      for (int r2 = 0; r2 < 4; ++r2) mx = fmaxf(mx, st[sb][r2]);
    mx = fmaxf(mx, __shfl_xor(mx, 16));
    mx = fmaxf(mx, __shfl_xor(mx, 32));
    const float mnew  = fmaxf(m, mx);
    const float alpha = __expf(m - mnew);
    m = mnew;
    float rs = 0.f;
#pragma unroll
    for (int sb = 0; sb < 4; ++sb)
#pragma unroll
      for (int r2 = 0; r2 < 4; ++r2) {
        float p = __expf(st[sb][r2] - mnew);
        st[sb][r2] = p;
        rs += p;
      }
    rs += __shfl_xor(rs, 16);
    rs += __shfl_xor(rs, 32);
    l = l * alpha + rs;

    // rescale O accumulator (O rows live at q = g*4 + reg)
    float ar[4];
#pragma unroll
    for (int r2 = 0; r2 < 4; ++r2) ar[r2] = __shfl(alpha, g * 4 + r2);
#pragma unroll
    for (int nb = 0; nb < 4; ++nb)
#pragma unroll
      for (int r2 = 0; r2 < 4; ++r2) acc[nb][r2] *= ar[r2];

    // ---------------- P -> bf16, A-operand layout via per-wave LDS ----------------
    {
      char* pw = psh + wv * 2048;
      const int sw = (qc & 7) << 4;
#pragma unroll
      for (int sb = 0; sb < 4; ++sb) {
        bf16x2 p0; p0[0] = (__bf16)st[sb][0]; p0[1] = (__bf16)st[sb][1];
        bf16x2 p1; p1[0] = (__bf16)st[sb][2]; p1[1] = (__bf16)st[sb][3];
        const int s0 = sb * 32 + g * 8;         // byte col of s = sb*16 + g*4
        *(bf16x2*)(pw + qc * 128 + ((s0)     ^ sw)) = p0;
        *(bf16x2*)(pw + qc * 128 + ((s0 + 4) ^ sw)) = p1;
      }
      asm volatile("s_waitcnt lgkmcnt(0)" ::: "memory");
    }

    // ---------------- PV: O += P · V ----------------
    {
      const char* pw = psh + wv * 2048;
      const int sw = (qc & 7) << 4;
      bf16x8 pa0 = *(const bf16x8*)(pw + qc * 128 + ((g * 16)      ^ sw));
      bf16x8 pa1 = *(const bf16x8*)(pw + qc * 128 + ((64 + g * 16) ^ sw));
#pragma unroll
      for (int nb = 0; nb < 4; ++nb) {
        const int vbase = (nb * 16 + qc) * 128;  // row = head-dim; (row&7)==(qc&7)
        bf16x8 v0f = *(const bf16x8*)(vtsh + vbase + ((g * 16)      ^ sw));
        bf16x8 v1f = *(const bf16x8*)(vtsh + vbase + ((64 + g * 16) ^ sw));
        acc[nb] = __builtin_amdgcn_mfma_f32_16x16x32_bf16(pa0, v0f, acc[nb], 0, 0, 0);
        acc[nb] = __builtin_amdgcn_mfma_f32_16x16x32_bf16(pa1, v1f, acc[nb], 0, 0, 0);
      }
    }
    __syncthreads();
  }

  // ---------------- epilogue: O /= l, store ----------------
  float linv[4];
#pragma unroll
  for (int r2 = 0; r2 < 4; ++r2) {
    float lr = __shfl(l, g * 4 + r2);
    linv[r2] = 1.0f / lr;
  }
#pragma unroll
  for (int nb = 0; nb < 4; ++nb)
#pragma unroll
    for (int r2 = 0; r2 < 4; ++r2) {
      const int row = qrow0 + g * 4 + r2;
      ob[(size_t)row * rstride + nb * 16 + qc] = acc[nb][r2] * linv[r2];
    }
}

extern "C" void kernel_launch(void* const* d_in, const int* in_sizes, int n_in,
                              void* d_out, int out_size, void* d_ws, size_t ws_size,
                              hipStream_t stream) {
  const float* q = (const float*)d_in[0];
  const float* k = (const float*)d_in[1];
  const float* v = (const float*)d_in[2];
  float* o = (float*)d_out;
  dim3 grid(LL / BQ, BB * NH);
  sdpa_fwd<<<grid, dim3(256), 0, stream>>>(q, k, v, o);
}

// Round 2
// 158.331 us; speedup vs baseline: 1.2815x; 1.2815x over previous
//
#include <hip/hip_runtime.h>
#include <hip/hip_bf16.h>
#include <math.h>

typedef __bf16 bf16x8 __attribute__((ext_vector_type(8)));
typedef __bf16 bf16x4 __attribute__((ext_vector_type(4)));
typedef float  f32x4  __attribute__((ext_vector_type(4)));

constexpr int EMBED = 1024;
constexpr int NH    = 16;
constexpr int HD    = 64;
constexpr int LL    = 2048;
constexpr int BB    = 2;
constexpr int SSEQ  = 2048;

constexpr int BQ = 64;          // q rows per block (4 waves x 16)
constexpr int BK = 64;          // kv rows per tile
constexpr int NT = SSEQ / BK;   // 32 tiles

// Workspace: K bf16 [b][h][s][d] (8 MiB) then V^T bf16 [b][h][d][s] (8 MiB)
constexpr size_t KW_ELEMS = (size_t)BB * NH * SSEQ * HD;

__device__ __forceinline__ void gload16(const void* g, void* l) {
  __builtin_amdgcn_global_load_lds((const __attribute__((address_space(1))) unsigned int*)g,
                                   (__attribute__((address_space(3))) unsigned int*)l, 16, 0, 0);
}

__device__ __forceinline__ float exp2_fast(float x) {
  float r;
  asm("v_exp_f32 %0, %1" : "=v"(r) : "v"(x));
  return r;
}

// ---- prepass: K -> bf16 [b][h][s][d]; V -> bf16 transposed [b][h][d][s] ----
__global__ __launch_bounds__(256) void prep_kv(const float* __restrict__ Kg,
                                               const float* __restrict__ Vg,
                                               __hip_bfloat16* __restrict__ kw,
                                               __hip_bfloat16* __restrict__ vtw) {
  const int bid = blockIdx.x;
  if (bid < 2048) {
    // K convert: idx -> (s, b, e8)
    const int idx = bid * 256 + threadIdx.x;
    const int e8 = idx & 127;
    const int t2 = idx >> 7;
    const int b  = t2 & 1;
    const int s  = t2 >> 1;
    const int h  = e8 >> 3;
    const int d8 = e8 & 7;
    const float* src = Kg + ((size_t)s * BB + b) * EMBED + e8 * 8;
    float4 a = *(const float4*)src;
    float4 c = *(const float4*)(src + 4);
    bf16x8 w;
    w[0] = (__bf16)a.x; w[1] = (__bf16)a.y; w[2] = (__bf16)a.z; w[3] = (__bf16)a.w;
    w[4] = (__bf16)c.x; w[5] = (__bf16)c.y; w[6] = (__bf16)c.z; w[7] = (__bf16)c.w;
    *(bf16x8*)(kw + (((size_t)(b * NH + h) * SSEQ + s) * HD + d8 * 8)) = w;
  } else {
    // V transpose-convert: idx -> (s8, b, e)
    const int idx = (bid - 2048) * 256 + threadIdx.x;
    const int e  = idx & 1023;
    const int t2 = idx >> 10;
    const int b  = t2 & 1;
    const int s0 = (t2 >> 1) * 8;
    const int h  = e >> 6;
    const int d  = e & 63;
    const float* src = Vg + ((size_t)s0 * BB + b) * EMBED + e;
    bf16x8 w;
#pragma unroll
    for (int i = 0; i < 8; ++i) w[i] = (__bf16)src[(size_t)i * BB * EMBED];
    *(bf16x8*)(vtw + (((size_t)(b * NH + h) * HD + d) * SSEQ + s0)) = w;
  }
}

// ---- hot kernel: flash attention over bf16 K / V^T ----
__global__ __launch_bounds__(256) void sdpa_fwd(const float* __restrict__ Qg,
                                                const __hip_bfloat16* __restrict__ Kw,
                                                const __hip_bfloat16* __restrict__ VTw,
                                                float* __restrict__ Og) {
  __shared__ char sh[40960];
  char* kbuf = sh;            // [2][8192] K tile, bf16 [64 s][64 d], swizzled content
  char* vbuf = sh + 16384;    // [2][8192] V^T tile, bf16 [64 d][64 s], swizzled content
  char* psh  = sh + 32768;    // [4][2048] per-wave P tile

  const int tid  = threadIdx.x;
  const int wv   = tid >> 6;
  const int lane = tid & 63;
  const int g    = lane >> 4;
  const int qc   = lane & 15;

  const int bh = blockIdx.y;
  const int bb = bh >> 4;
  const int hh = bh & 15;

  const size_t rstride = (size_t)BB * EMBED;
  const float* qb = Qg + (size_t)bb * EMBED + hh * HD;
  float*       ob = Og + (size_t)bb * EMBED + hh * HD;
  const char*  kwb = (const char*)(Kw + (size_t)bh * SSEQ * HD);
  const char*  vtb = (const char*)(VTw + (size_t)bh * HD * SSEQ);

  const int qrow0 = blockIdx.x * BQ + wv * 16;

  // staging source addresses (rule #21: linear LDS dest, inverse-swizzled source)
  const int r0  = (wv * 2 + 0) * 8 + (lane >> 3);
  const int r1  = (wv * 2 + 1) * 8 + (lane >> 3);
  const int ch0 = (lane & 7) ^ (r0 & 7);
  const int ch1 = (lane & 7) ^ (r1 & 7);
  const char* kg0 = kwb + r0 * 128 + ch0 * 16;   // +8192 per tile
  const char* kg1 = kwb + r1 * 128 + ch1 * 16;
  const char* vg0 = vtb + r0 * 4096 + ch0 * 16;  // +128 per tile
  const char* vg1 = vtb + r1 * 4096 + ch1 * 16;
  char* kd0 = kbuf + (wv * 2 + 0) * 1024;
  char* kd1 = kbuf + (wv * 2 + 1) * 1024;
  char* vd0 = vbuf + (wv * 2 + 0) * 1024;
  char* vd1 = vbuf + (wv * 2 + 1) * 1024;

#define STAGE(B, T)                                        \
  do {                                                     \
    gload16(kg0 + (size_t)(T) * 8192, kd0 + (B) * 8192);   \
    gload16(kg1 + (size_t)(T) * 8192, kd1 + (B) * 8192);   \
    gload16(vg0 + (size_t)(T) * 128,  vd0 + (B) * 8192);   \
    gload16(vg1 + (size_t)(T) * 128,  vd1 + (B) * 8192);   \
  } while (0)

  // ---- Q fragments (B-operand layout), scale folds 1/sqrt(64) * log2(e) ----
  constexpr float QSC = 0.125f * 1.4426950408889634f;
  bf16x8 qf[2];
  {
    const float* qr = qb + (size_t)(qrow0 + qc) * rstride;
#pragma unroll
    for (int f = 0; f < 2; ++f) {
      const float* p = qr + f * 32 + g * 8;
      float4 a = *(const float4*)p;
      float4 c = *(const float4*)(p + 4);
      qf[f][0] = (__bf16)(a.x * QSC); qf[f][1] = (__bf16)(a.y * QSC);
      qf[f][2] = (__bf16)(a.z * QSC); qf[f][3] = (__bf16)(a.w * QSC);
      qf[f][4] = (__bf16)(c.x * QSC); qf[f][5] = (__bf16)(c.y * QSC);
      qf[f][6] = (__bf16)(c.z * QSC); qf[f][7] = (__bf16)(c.w * QSC);
    }
  }

  f32x4 acc[4];
#pragma unroll
  for (int nb = 0; nb < 4; ++nb) { acc[nb][0] = 0.f; acc[nb][1] = 0.f; acc[nb][2] = 0.f; acc[nb][3] = 0.f; }
  float m = -INFINITY;
  float l = 0.f;

  STAGE(0, 0);
  __syncthreads();
  int cur = 0;

  for (int t = 0; t < NT; ++t) {
    if (t + 1 < NT) STAGE(cur ^ 1, t + 1);   // prefetch overlaps compute

    const char* kb = kbuf + cur * 8192;
    const char* vb = vbuf + cur * 8192;
    const int sw = (qc & 7) << 4;

    // ---- QK^T (swapped): S^T[s, q] = K · Q, in log2 units ----
    f32x4 st[4];
#pragma unroll
    for (int sb = 0; sb < 4; ++sb) {
      const int base = (sb * 16 + qc) * 128;
      bf16x8 k0 = *(const bf16x8*)(kb + base + ((g * 16)      ^ sw));
      bf16x8 k1 = *(const bf16x8*)(kb + base + ((64 + g * 16) ^ sw));
      f32x4 a; a[0] = 0.f; a[1] = 0.f; a[2] = 0.f; a[3] = 0.f;
      a = __builtin_amdgcn_mfma_f32_16x16x32_bf16(k0, qf[0], a, 0, 0, 0);
      a = __builtin_amdgcn_mfma_f32_16x16x32_bf16(k1, qf[1], a, 0, 0, 0);
      st[sb] = a;
    }

    // ---- online softmax (base-2), state lane q = qc ----
    float mx = st[0][0];
#pragma unroll
    for (int sb = 0; sb < 4; ++sb)
#pragma unroll
      for (int r2 = 0; r2 < 4; ++r2) mx = fmaxf(mx, st[sb][r2]);
    mx = fmaxf(mx, __shfl_xor(mx, 16));
    mx = fmaxf(mx, __shfl_xor(mx, 32));
    const float mnew  = fmaxf(m, mx);
    const float alpha = exp2_fast(m - mnew);
    m = mnew;
    float rs = 0.f;
#pragma unroll
    for (int sb = 0; sb < 4; ++sb)
#pragma unroll
      for (int r2 = 0; r2 < 4; ++r2) {
        float p = exp2_fast(st[sb][r2] - mnew);
        st[sb][r2] = p;
        rs += p;
      }
    rs += __shfl_xor(rs, 16);
    rs += __shfl_xor(rs, 32);
    l = l * alpha + rs;

    // rescale O accumulator (O rows live at q = g*4 + reg)
    float ar[4];
#pragma unroll
    for (int r2 = 0; r2 < 4; ++r2) ar[r2] = __shfl(alpha, g * 4 + r2);
#pragma unroll
    for (int nb = 0; nb < 4; ++nb)
#pragma unroll
      for (int r2 = 0; r2 < 4; ++r2) acc[nb][r2] *= ar[r2];

    // ---- P -> bf16, A-operand layout via per-wave LDS (b64 writes) ----
    {
      char* pw = psh + wv * 2048;
#pragma unroll
      for (int sb = 0; sb < 4; ++sb) {
        bf16x4 p4;
        p4[0] = (__bf16)st[sb][0]; p4[1] = (__bf16)st[sb][1];
        p4[2] = (__bf16)st[sb][2]; p4[3] = (__bf16)st[sb][3];
        *(bf16x4*)(pw + qc * 128 + ((sb * 32 + g * 8) ^ sw)) = p4;
      }
      asm volatile("s_waitcnt lgkmcnt(0)" ::: "memory");
    }

    // ---- PV: O += P · V ----
    {
      const char* pw = psh + wv * 2048;
      bf16x8 pa0 = *(const bf16x8*)(pw + qc * 128 + ((g * 16)      ^ sw));
      bf16x8 pa1 = *(const bf16x8*)(pw + qc * 128 + ((64 + g * 16) ^ sw));
#pragma unroll
      for (int nb = 0; nb < 4; ++nb) {
        const int vbase = (nb * 16 + qc) * 128;
        bf16x8 v0f = *(const bf16x8*)(vb + vbase + ((g * 16)      ^ sw));
        bf16x8 v1f = *(const bf16x8*)(vb + vbase + ((64 + g * 16) ^ sw));
        acc[nb] = __builtin_amdgcn_mfma_f32_16x16x32_bf16(pa0, v0f, acc[nb], 0, 0, 0);
        acc[nb] = __builtin_amdgcn_mfma_f32_16x16x32_bf16(pa1, v1f, acc[nb], 0, 0, 0);
      }
    }

    __syncthreads();   // drains vmcnt (prefetch landed) + all reads of buf[cur] done
    cur ^= 1;
  }
#undef STAGE

  // ---- epilogue: O /= l, store ----
  float linv[4];
#pragma unroll
  for (int r2 = 0; r2 < 4; ++r2) {
    float lr = __shfl(l, g * 4 + r2);
    linv[r2] = 1.0f / lr;
  }
#pragma unroll
  for (int nb = 0; nb < 4; ++nb)
#pragma unroll
    for (int r2 = 0; r2 < 4; ++r2) {
      const int row = qrow0 + g * 4 + r2;
      ob[(size_t)row * rstride + nb * 16 + qc] = acc[nb][r2] * linv[r2];
    }
}

extern "C" void kernel_launch(void* const* d_in, const int* in_sizes, int n_in,
                              void* d_out, int out_size, void* d_ws, size_t ws_size,
                              hipStream_t stream) {
  const float* q = (const float*)d_in[0];
  const float* k = (const float*)d_in[1];
  const float* v = (const float*)d_in[2];
  float* o = (float*)d_out;
  __hip_bfloat16* kw  = (__hip_bfloat16*)d_ws;
  __hip_bfloat16* vtw = kw + KW_ELEMS;

  prep_kv<<<dim3(4096), dim3(256), 0, stream>>>(k, v, kw, vtw);
  dim3 grid(LL / BQ, BB * NH);
  sdpa_fwd<<<grid, dim3(256), 0, stream>>>(q, kw, vtw, o);
}

// Round 3
// 154.525 us; speedup vs baseline: 1.3130x; 1.0246x over previous
//
#include <hip/hip_runtime.h>
#include <hip/hip_bf16.h>
#include <math.h>

typedef __bf16 bf16x8 __attribute__((ext_vector_type(8)));
typedef __bf16 bf16x4 __attribute__((ext_vector_type(4)));
typedef float  f32x4  __attribute__((ext_vector_type(4)));

constexpr int EMBED = 1024;
constexpr int NH    = 16;
constexpr int HD    = 64;
constexpr int LL    = 2048;
constexpr int BB    = 2;
constexpr int SSEQ  = 2048;

constexpr int BQ = 64;          // q rows per block (4 waves x 16)
constexpr int BK = 64;          // kv rows per tile
constexpr int NT = SSEQ / BK;   // 32 tiles

// Workspace: K bf16 [b][h][s][d] (8 MiB) then V^T bf16 [b][h][d][s] (8 MiB)
constexpr size_t KW_ELEMS = (size_t)BB * NH * SSEQ * HD;

__device__ __forceinline__ void gload16(const void* g, void* l) {
  __builtin_amdgcn_global_load_lds((const __attribute__((address_space(1))) unsigned int*)g,
                                   (__attribute__((address_space(3))) unsigned int*)l, 16, 0, 0);
}

__device__ __forceinline__ float exp2_fast(float x) {
  float r;
  asm("v_exp_f32 %0, %1" : "=v"(r) : "v"(x));
  return r;
}

// ---- prepass: K -> bf16 [b][h][s][d]; V -> bf16 transposed [b][h][d][s] ----
// V path: LDS-tiled 64x64 transpose per (b,h,s-tile) so BOTH global sides are
// coalesced. LDS layout: addr(s,d) = s*128 + ((d + (s>>3)*16) & 63)*2 — chunk
// rotation keeps the column gather <=4-way on banks and stores conflict-free.
__global__ __launch_bounds__(256) void prep_kv(const float* __restrict__ Kg,
                                               const float* __restrict__ Vg,
                                               __hip_bfloat16* __restrict__ kw,
                                               __hip_bfloat16* __restrict__ vtw) {
  __shared__ char tsh[64 * 128];
  const int bid = blockIdx.x;
  if (bid < 2048) {
    // K convert: idx -> (s, b, e8); coalesced-ish read, coalesced write
    const int idx = bid * 256 + threadIdx.x;
    const int e8 = idx & 127;
    const int t2 = idx >> 7;
    const int b  = t2 & 1;
    const int s  = t2 >> 1;
    const int h  = e8 >> 3;
    const int d8 = e8 & 7;
    const float* src = Kg + ((size_t)s * BB + b) * EMBED + e8 * 8;
    float4 a = *(const float4*)src;
    float4 c = *(const float4*)(src + 4);
    bf16x8 w;
    w[0] = (__bf16)a.x; w[1] = (__bf16)a.y; w[2] = (__bf16)a.z; w[3] = (__bf16)a.w;
    w[4] = (__bf16)c.x; w[5] = (__bf16)c.y; w[6] = (__bf16)c.z; w[7] = (__bf16)c.w;
    *(bf16x8*)(kw + (((size_t)(b * NH + h) * SSEQ + s) * HD + d8 * 8)) = w;
  } else {
    const int vb2 = bid - 2048;        // 0..1023
    const int st  = vb2 & 31;          // s-tile index
    const int bh  = vb2 >> 5;          // 0..31
    const int b   = bh >> 4;
    const int h   = bh & 15;
    const int t   = threadIdx.x;

    // --- load 64 s x 64 d tile, convert, store to swizzled LDS ---
    {
      const int r  = t >> 2;           // s row in tile
      const int c0 = (t & 3) * 16;     // d chunk
      const float* src = Vg + ((size_t)(st * 64 + r) * BB + b) * EMBED + h * HD + c0;
      float4 x0 = *(const float4*)(src);
      float4 x1 = *(const float4*)(src + 4);
      float4 x2 = *(const float4*)(src + 8);
      float4 x3 = *(const float4*)(src + 12);
      bf16x8 w0, w1;
      w0[0] = (__bf16)x0.x; w0[1] = (__bf16)x0.y; w0[2] = (__bf16)x0.z; w0[3] = (__bf16)x0.w;
      w0[4] = (__bf16)x1.x; w0[5] = (__bf16)x1.y; w0[6] = (__bf16)x1.z; w0[7] = (__bf16)x1.w;
      w1[0] = (__bf16)x2.x; w1[1] = (__bf16)x2.y; w1[2] = (__bf16)x2.z; w1[3] = (__bf16)x2.w;
      w1[4] = (__bf16)x3.x; w1[5] = (__bf16)x3.y; w1[6] = (__bf16)x3.z; w1[7] = (__bf16)x3.w;
      const int colb = ((c0 + (r >> 3) * 16) & 63) * 2;  // 32B-chunk aligned
      char* rowp = tsh + r * 128;
      *(bf16x8*)(rowp + colb)      = w0;
      *(bf16x8*)(rowp + colb + 16) = w1;
    }
    __syncthreads();
    // --- gather columns, write V^T coalesced ---
    {
      const int d   = t >> 2;          // head-dim row of V^T
      const int sc0 = (t & 3) * 16;    // s chunk
      bf16x8 o0, o1;
#pragma unroll
      for (int i = 0; i < 8; ++i) {
        const int s = sc0 + i;
        o0[i] = *(const __bf16*)(tsh + s * 128 + (((d + (s >> 3) * 16) & 63) * 2));
      }
#pragma unroll
      for (int i = 8; i < 16; ++i) {
        const int s = sc0 + i;
        o1[i - 8] = *(const __bf16*)(tsh + s * 128 + (((d + (s >> 3) * 16) & 63) * 2));
      }
      __hip_bfloat16* dst = vtw + ((size_t)(bh * HD + d)) * SSEQ + st * 64 + sc0;
      *(bf16x8*)(dst)     = o0;
      *(bf16x8*)(dst + 8) = o1;
    }
  }
}

// ---- hot kernel: flash attention over bf16 K / V^T ----
__global__ __launch_bounds__(256) void sdpa_fwd(const float* __restrict__ Qg,
                                                const __hip_bfloat16* __restrict__ Kw,
                                                const __hip_bfloat16* __restrict__ VTw,
                                                float* __restrict__ Og) {
  __shared__ char sh[40960];
  char* kbuf = sh;            // [2][8192] K tile, bf16 [64 s][64 d], swizzled content
  char* vbuf = sh + 16384;    // [2][8192] V^T tile, bf16 [64 d][64 s], swizzled content
  char* psh  = sh + 32768;    // [4][2048] per-wave P tile

  const int tid  = threadIdx.x;
  const int wv   = tid >> 6;
  const int lane = tid & 63;
  const int g    = lane >> 4;
  const int qc   = lane & 15;

  const int bh = blockIdx.y;
  const int bb = bh >> 4;
  const int hh = bh & 15;

  const size_t rstride = (size_t)BB * EMBED;
  const float* qb = Qg + (size_t)bb * EMBED + hh * HD;
  float*       ob = Og + (size_t)bb * EMBED + hh * HD;
  const char*  kwb = (const char*)(Kw + (size_t)bh * SSEQ * HD);
  const char*  vtb = (const char*)(VTw + (size_t)bh * HD * SSEQ);

  const int qrow0 = blockIdx.x * BQ + wv * 16;

  // staging source addresses (rule #21: linear LDS dest, inverse-swizzled source)
  const int r0  = (wv * 2 + 0) * 8 + (lane >> 3);
  const int r1  = (wv * 2 + 1) * 8 + (lane >> 3);
  const int ch0 = (lane & 7) ^ (r0 & 7);
  const int ch1 = (lane & 7) ^ (r1 & 7);
  const char* kg0 = kwb + r0 * 128 + ch0 * 16;   // +8192 per tile
  const char* kg1 = kwb + r1 * 128 + ch1 * 16;
  const char* vg0 = vtb + r0 * 4096 + ch0 * 16;  // +128 per tile
  const char* vg1 = vtb + r1 * 4096 + ch1 * 16;
  char* kd0 = kbuf + (wv * 2 + 0) * 1024;
  char* kd1 = kbuf + (wv * 2 + 1) * 1024;
  char* vd0 = vbuf + (wv * 2 + 0) * 1024;
  char* vd1 = vbuf + (wv * 2 + 1) * 1024;

#define STAGE(B, T)                                        \
  do {                                                     \
    gload16(kg0 + (size_t)(T) * 8192, kd0 + (B) * 8192);   \
    gload16(kg1 + (size_t)(T) * 8192, kd1 + (B) * 8192);   \
    gload16(vg0 + (size_t)(T) * 128,  vd0 + (B) * 8192);   \
    gload16(vg1 + (size_t)(T) * 128,  vd1 + (B) * 8192);   \
  } while (0)

  // ---- Q fragments (B-operand layout), scale folds 1/sqrt(64) * log2(e) ----
  constexpr float QSC = 0.125f * 1.4426950408889634f;
  bf16x8 qf[2];
  {
    const float* qr = qb + (size_t)(qrow0 + qc) * rstride;
#pragma unroll
    for (int f = 0; f < 2; ++f) {
      const float* p = qr + f * 32 + g * 8;
      float4 a = *(const float4*)p;
      float4 c = *(const float4*)(p + 4);
      qf[f][0] = (__bf16)(a.x * QSC); qf[f][1] = (__bf16)(a.y * QSC);
      qf[f][2] = (__bf16)(a.z * QSC); qf[f][3] = (__bf16)(a.w * QSC);
      qf[f][4] = (__bf16)(c.x * QSC); qf[f][5] = (__bf16)(c.y * QSC);
      qf[f][6] = (__bf16)(c.z * QSC); qf[f][7] = (__bf16)(c.w * QSC);
    }
  }

  f32x4 acc[4];
#pragma unroll
  for (int nb = 0; nb < 4; ++nb) { acc[nb][0] = 0.f; acc[nb][1] = 0.f; acc[nb][2] = 0.f; acc[nb][3] = 0.f; }
  float m = -INFINITY;
  float l = 0.f;

  STAGE(0, 0);
  __syncthreads();
  int cur = 0;

  for (int t = 0; t < NT; ++t) {
    if (t + 1 < NT) STAGE(cur ^ 1, t + 1);   // prefetch overlaps compute

    const char* kb = kbuf + cur * 8192;
    const char* vb = vbuf + cur * 8192;
    const int sw = (qc & 7) << 4;

    // ---- QK^T (swapped): S^T[s, q] = K · Q, in log2 units ----
    f32x4 st[4];
    __builtin_amdgcn_s_setprio(1);
#pragma unroll
    for (int sb = 0; sb < 4; ++sb) {
      const int base = (sb * 16 + qc) * 128;
      bf16x8 k0 = *(const bf16x8*)(kb + base + ((g * 16)      ^ sw));
      bf16x8 k1 = *(const bf16x8*)(kb + base + ((64 + g * 16) ^ sw));
      f32x4 a; a[0] = 0.f; a[1] = 0.f; a[2] = 0.f; a[3] = 0.f;
      a = __builtin_amdgcn_mfma_f32_16x16x32_bf16(k0, qf[0], a, 0, 0, 0);
      a = __builtin_amdgcn_mfma_f32_16x16x32_bf16(k1, qf[1], a, 0, 0, 0);
      st[sb] = a;
    }
    __builtin_amdgcn_s_setprio(0);

    // ---- online softmax (base-2), state lane q = qc ----
    float mx;
    {
      float m0 = fmaxf(fmaxf(st[0][0], st[0][1]), fmaxf(st[0][2], st[0][3]));
      float m1 = fmaxf(fmaxf(st[1][0], st[1][1]), fmaxf(st[1][2], st[1][3]));
      float m2 = fmaxf(fmaxf(st[2][0], st[2][1]), fmaxf(st[2][2], st[2][3]));
      float m3 = fmaxf(fmaxf(st[3][0], st[3][1]), fmaxf(st[3][2], st[3][3]));
      mx = fmaxf(fmaxf(m0, m1), fmaxf(m2, m3));
    }
    mx = fmaxf(mx, __shfl_xor(mx, 16));
    mx = fmaxf(mx, __shfl_xor(mx, 32));

    // T13 defer-max: only rescale when the running max grows by > 8 (log2
    // units, so deferred P <= 256 — safe in bf16/fp32). m starts at -inf so
    // the first tile always takes the branch (alpha = exp2(-inf) = 0).
    if (!__all(mx - m <= 8.0f)) {
      const float mnew  = fmaxf(m, mx);
      const float alpha = exp2_fast(m - mnew);
      m = mnew;
      l *= alpha;
      float ar[4];
#pragma unroll
      for (int r2 = 0; r2 < 4; ++r2) ar[r2] = __shfl(alpha, g * 4 + r2);
#pragma unroll
      for (int nb = 0; nb < 4; ++nb)
#pragma unroll
        for (int r2 = 0; r2 < 4; ++r2) acc[nb][r2] *= ar[r2];
    }

    float rs = 0.f;
#pragma unroll
    for (int sb = 0; sb < 4; ++sb)
#pragma unroll
      for (int r2 = 0; r2 < 4; ++r2) {
        float p = exp2_fast(st[sb][r2] - m);
        st[sb][r2] = p;
        rs += p;
      }
    rs += __shfl_xor(rs, 16);
    rs += __shfl_xor(rs, 32);
    l += rs;

    // ---- P -> bf16, A-operand layout via per-wave LDS (b64 writes) ----
    {
      char* pw = psh + wv * 2048;
#pragma unroll
      for (int sb = 0; sb < 4; ++sb) {
        bf16x4 p4;
        p4[0] = (__bf16)st[sb][0]; p4[1] = (__bf16)st[sb][1];
        p4[2] = (__bf16)st[sb][2]; p4[3] = (__bf16)st[sb][3];
        *(bf16x4*)(pw + qc * 128 + ((sb * 32 + g * 8) ^ sw)) = p4;
      }
      asm volatile("s_waitcnt lgkmcnt(0)" ::: "memory");
    }

    // ---- PV: O += P · V ----
    {
      const char* pw = psh + wv * 2048;
      bf16x8 pa0 = *(const bf16x8*)(pw + qc * 128 + ((g * 16)      ^ sw));
      bf16x8 pa1 = *(const bf16x8*)(pw + qc * 128 + ((64 + g * 16) ^ sw));
      __builtin_amdgcn_s_setprio(1);
#pragma unroll
      for (int nb = 0; nb < 4; ++nb) {
        const int vbase = (nb * 16 + qc) * 128;
        bf16x8 v0f = *(const bf16x8*)(vb + vbase + ((g * 16)      ^ sw));
        bf16x8 v1f = *(const bf16x8*)(vb + vbase + ((64 + g * 16) ^ sw));
        acc[nb] = __builtin_amdgcn_mfma_f32_16x16x32_bf16(pa0, v0f, acc[nb], 0, 0, 0);
        acc[nb] = __builtin_amdgcn_mfma_f32_16x16x32_bf16(pa1, v1f, acc[nb], 0, 0, 0);
      }
      __builtin_amdgcn_s_setprio(0);
    }

    __syncthreads();   // drains vmcnt (prefetch landed) + all reads of buf[cur] done
    cur ^= 1;
  }
#undef STAGE

  // ---- epilogue: O /= l, store ----
  float linv[4];
#pragma unroll
  for (int r2 = 0; r2 < 4; ++r2) {
    float lr = __shfl(l, g * 4 + r2);
    linv[r2] = 1.0f / lr;
  }
#pragma unroll
  for (int nb = 0; nb < 4; ++nb)
#pragma unroll
    for (int r2 = 0; r2 < 4; ++r2) {
      const int row = qrow0 + g * 4 + r2;
      ob[(size_t)row * rstride + nb * 16 + qc] = acc[nb][r2] * linv[r2];
    }
}

extern "C" void kernel_launch(void* const* d_in, const int* in_sizes, int n_in,
                              void* d_out, int out_size, void* d_ws, size_t ws_size,
                              hipStream_t stream) {
  const float* q = (const float*)d_in[0];
  const float* k = (const float*)d_in[1];
  const float* v = (const float*)d_in[2];
  float* o = (float*)d_out;
  __hip_bfloat16* kw  = (__hip_bfloat16*)d_ws;
  __hip_bfloat16* vtw = kw + KW_ELEMS;

  prep_kv<<<dim3(3072), dim3(256), 0, stream>>>(k, v, kw, vtw);
  dim3 grid(LL / BQ, BB * NH);
  sdpa_fwd<<<grid, dim3(256), 0, stream>>>(q, kw, vtw, o);
}

// Round 4
// 140.997 us; speedup vs baseline: 1.4390x; 1.0959x over previous
//
#include <hip/hip_runtime.h>
#include <hip/hip_bf16.h>
#include <math.h>

typedef __bf16 bf16x8 __attribute__((ext_vector_type(8)));
typedef __bf16 bf16x4 __attribute__((ext_vector_type(4)));
typedef float  f32x4  __attribute__((ext_vector_type(4)));

constexpr int EMBED = 1024;
constexpr int NH    = 16;
constexpr int HD    = 64;
constexpr int LL    = 2048;
constexpr int BB    = 2;
constexpr int SSEQ  = 2048;

constexpr int BQ = 128;         // q rows per block (8 waves x 16)
constexpr int BK = 64;          // kv rows per tile
constexpr int NT = SSEQ / BK;   // 32 tiles

// Workspace: K bf16 [b][h][s][d] (8 MiB) then V^T bf16 [b][h][d][s] (8 MiB)
constexpr size_t KW_ELEMS = (size_t)BB * NH * SSEQ * HD;

__device__ __forceinline__ void gload16(const void* g, void* l) {
  __builtin_amdgcn_global_load_lds((const __attribute__((address_space(1))) unsigned int*)g,
                                   (__attribute__((address_space(3))) unsigned int*)l, 16, 0, 0);
}

__device__ __forceinline__ float exp2_fast(float x) {
  float r;
  asm("v_exp_f32 %0, %1" : "=v"(r) : "v"(x));
  return r;
}

// ---- prepass: K -> bf16 [b][h][s][d]; V -> bf16 transposed [b][h][d][s] ----
__global__ __launch_bounds__(256) void prep_kv(const float* __restrict__ Kg,
                                               const float* __restrict__ Vg,
                                               __hip_bfloat16* __restrict__ kw,
                                               __hip_bfloat16* __restrict__ vtw) {
  __shared__ char tsh[64 * 128];
  const int bid = blockIdx.x;
  if (bid < 2048) {
    const int idx = bid * 256 + threadIdx.x;
    const int e8 = idx & 127;
    const int t2 = idx >> 7;
    const int b  = t2 & 1;
    const int s  = t2 >> 1;
    const int h  = e8 >> 3;
    const int d8 = e8 & 7;
    const float* src = Kg + ((size_t)s * BB + b) * EMBED + e8 * 8;
    float4 a = *(const float4*)src;
    float4 c = *(const float4*)(src + 4);
    bf16x8 w;
    w[0] = (__bf16)a.x; w[1] = (__bf16)a.y; w[2] = (__bf16)a.z; w[3] = (__bf16)a.w;
    w[4] = (__bf16)c.x; w[5] = (__bf16)c.y; w[6] = (__bf16)c.z; w[7] = (__bf16)c.w;
    *(bf16x8*)(kw + (((size_t)(b * NH + h) * SSEQ + s) * HD + d8 * 8)) = w;
  } else {
    const int vb2 = bid - 2048;
    const int st  = vb2 & 31;
    const int bh  = vb2 >> 5;
    const int b   = bh >> 4;
    const int h   = bh & 15;
    const int t   = threadIdx.x;
    {
      const int r  = t >> 2;
      const int c0 = (t & 3) * 16;
      const float* src = Vg + ((size_t)(st * 64 + r) * BB + b) * EMBED + h * HD + c0;
      float4 x0 = *(const float4*)(src);
      float4 x1 = *(const float4*)(src + 4);
      float4 x2 = *(const float4*)(src + 8);
      float4 x3 = *(const float4*)(src + 12);
      bf16x8 w0, w1;
      w0[0] = (__bf16)x0.x; w0[1] = (__bf16)x0.y; w0[2] = (__bf16)x0.z; w0[3] = (__bf16)x0.w;
      w0[4] = (__bf16)x1.x; w0[5] = (__bf16)x1.y; w0[6] = (__bf16)x1.z; w0[7] = (__bf16)x1.w;
      w1[0] = (__bf16)x2.x; w1[1] = (__bf16)x2.y; w1[2] = (__bf16)x2.z; w1[3] = (__bf16)x2.w;
      w1[4] = (__bf16)x3.x; w1[5] = (__bf16)x3.y; w1[6] = (__bf16)x3.z; w1[7] = (__bf16)x3.w;
      const int colb = ((c0 + (r >> 3) * 16) & 63) * 2;
      char* rowp = tsh + r * 128;
      *(bf16x8*)(rowp + colb)      = w0;
      *(bf16x8*)(rowp + colb + 16) = w1;
    }
    __syncthreads();
    {
      const int d   = t >> 2;
      const int sc0 = (t & 3) * 16;
      bf16x8 o0, o1;
#pragma unroll
      for (int i = 0; i < 8; ++i) {
        const int s = sc0 + i;
        o0[i] = *(const __bf16*)(tsh + s * 128 + (((d + (s >> 3) * 16) & 63) * 2));
      }
#pragma unroll
      for (int i = 8; i < 16; ++i) {
        const int s = sc0 + i;
        o1[i - 8] = *(const __bf16*)(tsh + s * 128 + (((d + (s >> 3) * 16) & 63) * 2));
      }
      __hip_bfloat16* dst = vtw + ((size_t)(bh * HD + d)) * SSEQ + st * 64 + sc0;
      *(bf16x8*)(dst)     = o0;
      *(bf16x8*)(dst + 8) = o1;
    }
  }
}

// ---- hot kernel: flash attention over bf16 K / V^T, 8 waves, BQ=128 ----
__global__ __launch_bounds__(512) void sdpa_fwd(const float* __restrict__ Qg,
                                                const __hip_bfloat16* __restrict__ Kw,
                                                const __hip_bfloat16* __restrict__ VTw,
                                                float* __restrict__ Og) {
  __shared__ char sh[49152];
  char* kbuf = sh;            // [2][8192] K tile
  char* vbuf = sh + 16384;    // [2][8192] V^T tile
  char* psh  = sh + 32768;    // [8][2048] per-wave P tile

  const int tid  = threadIdx.x;
  const int wv   = tid >> 6;
  const int lane = tid & 63;
  const int g    = lane >> 4;
  const int qc   = lane & 15;

  // XCD-clustered decode: all 16 q-blocks of a head land on one XCD
  // (dispatch round-robins blockIdx across 8 XCDs: xcd = bid & 7).
  const int bid = blockIdx.x;
  const int xcd = bid & 7;
  const int rest = bid >> 3;
  const int qb  = rest & 15;
  const int bh  = ((rest >> 4) << 3) | xcd;
  const int bb  = bh >> 4;
  const int hh  = bh & 15;

  const size_t rstride = (size_t)BB * EMBED;
  const float* qb_ptr = Qg + (size_t)bb * EMBED + hh * HD;
  float*       ob     = Og + (size_t)bb * EMBED + hh * HD;
  const char*  kwb = (const char*)(Kw + (size_t)bh * SSEQ * HD);
  const char*  vtb = (const char*)(VTw + (size_t)bh * HD * SSEQ);

  const int qrow0 = qb * BQ + wv * 16;

  // staging: wave wv covers tile rows wv*8 .. wv*8+7 (lane -> row, chunk)
  const int rW = wv * 8 + (lane >> 3);
  const int cW = (lane & 7) ^ (rW & 7);          // inverse swizzle on source
  const char* kgS = kwb + rW * 128 + cW * 16;    // + T*8192
  const char* vgS = vtb + (size_t)rW * 4096 + cW * 16;  // + T*128
  char* kdS = kbuf + wv * 1024;                  // wave-uniform LDS base (+B*8192)
  char* vdS = vbuf + wv * 1024;

#define STAGE(B, T)                                       \
  do {                                                    \
    gload16(kgS + (size_t)(T) * 8192, kdS + (B) * 8192);  \
    gload16(vgS + (size_t)(T) * 128,  vdS + (B) * 8192);  \
  } while (0)

  // ---- Q fragments (B-operand layout); scale folds 1/8 * log2(e) ----
  constexpr float QSC = 0.125f * 1.4426950408889634f;
  bf16x8 qf[2];
  {
    const float* qr = qb_ptr + (size_t)(qrow0 + qc) * rstride;
#pragma unroll
    for (int f = 0; f < 2; ++f) {
      const float* p = qr + f * 32 + g * 8;
      float4 a = *(const float4*)p;
      float4 c = *(const float4*)(p + 4);
      qf[f][0] = (__bf16)(a.x * QSC); qf[f][1] = (__bf16)(a.y * QSC);
      qf[f][2] = (__bf16)(a.z * QSC); qf[f][3] = (__bf16)(a.w * QSC);
      qf[f][4] = (__bf16)(c.x * QSC); qf[f][5] = (__bf16)(c.y * QSC);
      qf[f][6] = (__bf16)(c.z * QSC); qf[f][7] = (__bf16)(c.w * QSC);
    }
  }

  f32x4 acc[4];
#pragma unroll
  for (int nb = 0; nb < 4; ++nb) { acc[nb][0] = 0.f; acc[nb][1] = 0.f; acc[nb][2] = 0.f; acc[nb][3] = 0.f; }
  float m = -INFINITY;
  float l = 0.f;

  const int sw = (qc & 7) << 4;
  char* pw = psh + wv * 2048;

  // one tile's compute against buffer at constant byte offset KOFF/VOFF
#define TILE(KOFF, VOFF)                                                      \
  do {                                                                        \
    const char* kb = kbuf + (KOFF);                                           \
    const char* vb = vbuf + (VOFF);                                           \
    f32x4 st[4];                                                              \
    __builtin_amdgcn_s_setprio(1);                                            \
    _Pragma("unroll")                                                         \
    for (int sb = 0; sb < 4; ++sb) {                                          \
      const int base = (sb * 16 + qc) * 128;                                  \
      bf16x8 k0 = *(const bf16x8*)(kb + base + ((g * 16)      ^ sw));         \
      bf16x8 k1 = *(const bf16x8*)(kb + base + ((64 + g * 16) ^ sw));         \
      f32x4 a; a[0] = 0.f; a[1] = 0.f; a[2] = 0.f; a[3] = 0.f;                \
      a = __builtin_amdgcn_mfma_f32_16x16x32_bf16(k0, qf[0], a, 0, 0, 0);     \
      a = __builtin_amdgcn_mfma_f32_16x16x32_bf16(k1, qf[1], a, 0, 0, 0);     \
      st[sb] = a;                                                             \
    }                                                                         \
    __builtin_amdgcn_s_setprio(0);                                            \
    float mx = fmaxf(fmaxf(fmaxf(st[0][0], st[0][1]), st[0][2]),              \
                     fmaxf(fmaxf(st[0][3], st[1][0]), st[1][1]));             \
    mx = fmaxf(mx, fmaxf(fmaxf(st[1][2], st[1][3]), st[2][0]));               \
    mx = fmaxf(mx, fmaxf(fmaxf(st[2][1], st[2][2]), st[2][3]));               \
    mx = fmaxf(mx, fmaxf(fmaxf(st[3][0], st[3][1]),                           \
                         fmaxf(st[3][2], st[3][3])));                         \
    mx = fmaxf(mx, __shfl_xor(mx, 16));                                       \
    mx = fmaxf(mx, __shfl_xor(mx, 32));                                       \
    if (!__all(mx - m <= 8.0f)) {                                             \
      const float mnew  = fmaxf(m, mx);                                       \
      const float alpha = exp2_fast(m - mnew);                                \
      m = mnew;                                                               \
      l *= alpha;                                                             \
      float ar[4];                                                            \
      _Pragma("unroll")                                                       \
      for (int r2 = 0; r2 < 4; ++r2) ar[r2] = __shfl(alpha, g * 4 + r2);      \
      _Pragma("unroll")                                                       \
      for (int nb = 0; nb < 4; ++nb)                                          \
        _Pragma("unroll")                                                     \
        for (int r2 = 0; r2 < 4; ++r2) acc[nb][r2] *= ar[r2];                 \
    }                                                                         \
    float rs = 0.f;                                                           \
    _Pragma("unroll")                                                         \
    for (int sb = 0; sb < 4; ++sb)                                            \
      _Pragma("unroll")                                                       \
      for (int r2 = 0; r2 < 4; ++r2) {                                        \
        float p = exp2_fast(st[sb][r2] - m);                                  \
        st[sb][r2] = p;                                                       \
        rs += p;                                                              \
      }                                                                       \
    rs += __shfl_xor(rs, 16);                                                 \
    rs += __shfl_xor(rs, 32);                                                 \
    l += rs;                                                                  \
    _Pragma("unroll")                                                         \
    for (int sb = 0; sb < 4; ++sb) {                                          \
      bf16x4 p4;                                                              \
      p4[0] = (__bf16)st[sb][0]; p4[1] = (__bf16)st[sb][1];                   \
      p4[2] = (__bf16)st[sb][2]; p4[3] = (__bf16)st[sb][3];                   \
      *(bf16x4*)(pw + qc * 128 + ((sb * 32 + g * 8) ^ sw)) = p4;              \
    }                                                                         \
    asm volatile("s_waitcnt lgkmcnt(0)" ::: "memory");                        \
    {                                                                         \
      bf16x8 pa0 = *(const bf16x8*)(pw + qc * 128 + ((g * 16)      ^ sw));    \
      bf16x8 pa1 = *(const bf16x8*)(pw + qc * 128 + ((64 + g * 16) ^ sw));    \
      __builtin_amdgcn_s_setprio(1);                                          \
      _Pragma("unroll")                                                       \
      for (int nb = 0; nb < 4; ++nb) {                                        \
        const int vbase = (nb * 16 + qc) * 128;                               \
        bf16x8 v0f = *(const bf16x8*)(vb + vbase + ((g * 16)      ^ sw));     \
        bf16x8 v1f = *(const bf16x8*)(vb + vbase + ((64 + g * 16) ^ sw));     \
        acc[nb] = __builtin_amdgcn_mfma_f32_16x16x32_bf16(pa0, v0f, acc[nb], 0, 0, 0); \
        acc[nb] = __builtin_amdgcn_mfma_f32_16x16x32_bf16(pa1, v1f, acc[nb], 0, 0, 0); \
      }                                                                       \
      __builtin_amdgcn_s_setprio(0);                                          \
    }                                                                         \
  } while (0)

  STAGE(0, 0);
  __syncthreads();

  for (int t = 0; t < NT; t += 2) {
    if (t + 1 < NT) STAGE(1, t + 1);
    TILE(0, 0);
    __syncthreads();
    if (t + 2 < NT) STAGE(0, t + 2);
    TILE(8192, 8192);
    __syncthreads();
  }
#undef STAGE
#undef TILE

  // ---- epilogue: O /= l, store ----
  float linv[4];
#pragma unroll
  for (int r2 = 0; r2 < 4; ++r2) {
    float lr = __shfl(l, g * 4 + r2);
    linv[r2] = 1.0f / lr;
  }
#pragma unroll
  for (int nb = 0; nb < 4; ++nb)
#pragma unroll
    for (int r2 = 0; r2 < 4; ++r2) {
      const int row = qrow0 + g * 4 + r2;
      ob[(size_t)row * rstride + nb * 16 + qc] = acc[nb][r2] * linv[r2];
    }
}

extern "C" void kernel_launch(void* const* d_in, const int* in_sizes, int n_in,
                              void* d_out, int out_size, void* d_ws, size_t ws_size,
                              hipStream_t stream) {
  const float* q = (const float*)d_in[0];
  const float* k = (const float*)d_in[1];
  const float* v = (const float*)d_in[2];
  float* o = (float*)d_out;
  __hip_bfloat16* kw  = (__hip_bfloat16*)d_ws;
  __hip_bfloat16* vtw = kw + KW_ELEMS;

  prep_kv<<<dim3(3072), dim3(256), 0, stream>>>(k, v, kw, vtw);
  sdpa_fwd<<<dim3(512), dim3(512), 0, stream>>>(q, kw, vtw, o);
}